// Round 5
// baseline (752.492 us; speedup 1.0000x reference)
//
#include <hip/hip_runtime.h>
#include <hip/hip_bf16.h>

typedef __hip_bfloat16 bf16;
typedef __attribute__((ext_vector_type(8))) short bf16x8;
typedef __attribute__((ext_vector_type(4))) short short4v;
typedef __attribute__((ext_vector_type(4))) float f32x4;

#define D128 128

// fast sigmoid: rcp(1+exp2(-x*log2e)) — error ~1e-7 rel, far below bf16 ulp
__device__ __forceinline__ float sigf(float x) {
    float e = __builtin_amdgcn_exp2f(-1.44269504f * x);
    return __builtin_amdgcn_rcpf(1.0f + e);
}

__device__ __forceinline__ short bf2s(bf16 h) { union { bf16 h; short s; } u; u.h = h; return u.s; }
__device__ __forceinline__ float s2f(short s) { union { short s; bf16 h; } u; u.s = s; return __bfloat162float(u.h); }

__device__ __forceinline__ float loadf(const void* p, size_t off, int isbf) {
    return isbf ? __bfloat162float(((const bf16*)p)[off]) : ((const float*)p)[off];
}

// ---------------------------------------------------------------------------
// Dtype sniffer: count bf16 exponent-all-ones patterns in first 16384 ushorts
// of g_feat. bf16 N(0,1) -> 0; f32-as-ushorts -> ~32. (*cnt==0) == "bf16".
// ---------------------------------------------------------------------------
__global__ __launch_bounds__(256) void sniff_kernel(const unsigned short* __restrict__ g,
                                                    int* __restrict__ cnt) {
    int t = threadIdx.x;
    int c = 0;
    for (int i = t; i < 16384; i += 256) {
        unsigned short u = g[i];
        if ((u & 0x7F80u) == 0x7F80u) c++;
    }
    #pragma unroll
    for (int o = 32; o >= 1; o >>= 1) c += __shfl_xor(c, o);
    __shared__ int sh[4];
    if ((t & 63) == 0) sh[t >> 6] = c;
    __syncthreads();
    if (t == 0) *cnt = sh[0] + sh[1] + sh[2] + sh[3];
}

// ---------------------------------------------------------------------------
// Cooperative W stage (512 threads): W (128 x K raw) -> LDS bf16 fragments,
// A-operand order: wlds[(t*KCH+c)*64+l] = W[t*16+(l&15)][c*32+(l>>4)*8 ..+8].
// ---------------------------------------------------------------------------
template <int KCH>
__device__ __forceinline__ void stage_W(const void* __restrict__ W, bf16x8* wlds,
                                        int tid, int isbf) {
    const int K = KCH * 32;
    if (isbf) {
        #pragma unroll
        for (int k = 0; k < (8 * KCH * 64) / 512; ++k) {
            int f = k * 512 + tid;
            int t = f / (KCH * 64);
            int c = (f / 64) % KCH;
            int l = f & 63;
            wlds[f] = *reinterpret_cast<const bf16x8*>(
                (const bf16*)W + (size_t)(t * 16 + (l & 15)) * K + c * 32 + (l >> 4) * 8);
        }
    } else {
        #pragma unroll
        for (int k = 0; k < (8 * KCH * 64) / 512; ++k) {
            int f = k * 512 + tid;
            int t = f / (KCH * 64);
            int c = (f / 64) % KCH;
            int l = f & 63;
            const f32x4* src = reinterpret_cast<const f32x4*>(
                (const float*)W + (size_t)(t * 16 + (l & 15)) * K + c * 32 + (l >> 4) * 8);
            f32x4 a = src[0], b = src[1];
            bf16x8 r;
            #pragma unroll
            for (int j = 0; j < 4; ++j) {
                r[j] = bf2s(__float2bfloat16(a[j]));
                r[4 + j] = bf2s(__float2bfloat16(b[j]));
            }
            wlds[f] = r;
        }
    }
}

// bias[t*16+quad*4 .. +3] -> bb[t][0..3], tile-invariant
__device__ __forceinline__ void load_bias(const void* __restrict__ bias, int quad,
                                          int isbf, float bb[8][4]) {
    if (isbf) {
        #pragma unroll
        for (int t = 0; t < 8; ++t) {
            short4v s = *reinterpret_cast<const short4v*>((const bf16*)bias + t * 16 + quad * 4);
            #pragma unroll
            for (int i = 0; i < 4; ++i) bb[t][i] = s2f(s[i]);
        }
    } else {
        #pragma unroll
        for (int t = 0; t < 8; ++t) {
            f32x4 s = *reinterpret_cast<const f32x4*>((const float*)bias + t * 16 + quad * 4);
            #pragma unroll
            for (int i = 0; i < 4; ++i) bb[t][i] = s[i];
        }
    }
}

// ---------------------------------------------------------------------------
// Fused: out = inorm(inorm(X) @ W^T + b). W in LDS (32 KB). 512-thread blocks,
// persistent waves grid-striding over 16-row tiles, no barriers after stage.
// MFMA operands: W = A (m=wcol), X = B (n=xrow) -> lane holds 4 consecutive
// output cols of one row -> 8 B packed stores; row reductions = xor 16,32.
// ---------------------------------------------------------------------------
__global__ __launch_bounds__(512) void ngn_kernel(const void* __restrict__ X,
                                                  const void* __restrict__ W,
                                                  const void* __restrict__ bias,
                                                  bf16* __restrict__ out, int N,
                                                  const int* __restrict__ cnt) {
    __shared__ bf16x8 wlds[8 * 4 * 64];  // 32 KB
    int isbf = (*cnt == 0);
    int tid = threadIdx.x;
    stage_W<4>(W, wlds, tid, isbf);
    int wave = tid >> 6, lane = tid & 63;
    int quad = lane >> 4, l16 = lane & 15;
    float bb[8][4];
    load_bias(bias, quad, isbf, bb);
    __syncthreads();

    int ntiles = N >> 4;
    int wstep = gridDim.x * 8;
    for (int tile = blockIdx.x * 8 + wave; tile < ntiles; tile += wstep) {
        int mrow = min(tile * 16 + l16, N - 1);
        // load input row, first inorm (row spread across quads, same l16)
        float x[4][8];
        if (isbf) {
            #pragma unroll
            for (int c = 0; c < 4; ++c) {
                bf16x8 v = *reinterpret_cast<const bf16x8*>(
                    (const bf16*)X + (size_t)mrow * D128 + c * 32 + quad * 8);
                #pragma unroll
                for (int j = 0; j < 8; ++j) x[c][j] = s2f(v[j]);
            }
        } else {
            #pragma unroll
            for (int c = 0; c < 4; ++c) {
                const f32x4* f = reinterpret_cast<const f32x4*>(
                    (const float*)X + (size_t)mrow * D128 + c * 32 + quad * 8);
                f32x4 a = f[0], b = f[1];
                #pragma unroll
                for (int j = 0; j < 4; ++j) { x[c][j] = a[j]; x[c][4 + j] = b[j]; }
            }
        }
        float s = 0.f, ss = 0.f;
        #pragma unroll
        for (int c = 0; c < 4; ++c)
            #pragma unroll
            for (int j = 0; j < 8; ++j) { s += x[c][j]; ss += x[c][j] * x[c][j]; }
        s += __shfl_xor(s, 16); ss += __shfl_xor(ss, 16);
        s += __shfl_xor(s, 32); ss += __shfl_xor(ss, 32);
        float mean = s * (1.0f / 128.0f);
        float var = ss * (1.0f / 128.0f) - mean * mean;
        float rinv = rsqrtf(fmaxf(var, 0.f) + 1e-5f);

        bf16x8 af[4];
        #pragma unroll
        for (int c = 0; c < 4; ++c)
            #pragma unroll
            for (int j = 0; j < 8; ++j)
                af[c][j] = bf2s(__float2bfloat16((x[c][j] - mean) * rinv));

        f32x4 acc[8] = {};
        #pragma unroll
        for (int t = 0; t < 8; ++t)
            #pragma unroll
            for (int c = 0; c < 4; ++c)
                acc[t] = __builtin_amdgcn_mfma_f32_16x16x32_bf16(
                    wlds[(t * 4 + c) * 64 + lane], af[c], acc[t], 0, 0, 0);

        // + bias, second inorm over output row mrow (32 in-lane + quads)
        float vals[8][4];
        float s2 = 0.f, ss2 = 0.f;
        #pragma unroll
        for (int t = 0; t < 8; ++t)
            #pragma unroll
            for (int i = 0; i < 4; ++i) {
                float v = acc[t][i] + bb[t][i];
                vals[t][i] = v;
                s2 += v; ss2 += v * v;
            }
        s2 += __shfl_xor(s2, 16); ss2 += __shfl_xor(ss2, 16);
        s2 += __shfl_xor(s2, 32); ss2 += __shfl_xor(ss2, 32);
        float m2 = s2 * (1.0f / 128.0f);
        float v2 = ss2 * (1.0f / 128.0f) - m2 * m2;
        float r2 = rsqrtf(fmaxf(v2, 0.f) + 1e-5f);
        #pragma unroll
        for (int t = 0; t < 8; ++t) {
            short4v pk;
            #pragma unroll
            for (int i = 0; i < 4; ++i)
                pk[i] = bf2s(__float2bfloat16((vals[t][i] - m2) * r2));
            *reinterpret_cast<short4v*>(out + (size_t)mrow * D128 + t * 16 + quad * 4) = pk;
        }
    }
}

// ---------------------------------------------------------------------------
// GEMM: out = act(X @ W^T + b). Same persistent/swapped structure as ngn.
// A0 raw input (flag-typed if A0RT, else f32); A1 bf16 ws buffer (concat
// second half when KCH==8). ACT: 1 sigmoid, 2 sig(relu). In-place out==A1
// safe: each lane reads exactly the row it writes; tiles disjoint per wave.
// ---------------------------------------------------------------------------
template <int KCH, int ACT, bool A0RT>
__global__ __launch_bounds__(512) void gemm_kernel(const void* __restrict__ A0,
                                                   const bf16* __restrict__ A1,
                                                   const void* __restrict__ W,
                                                   const void* __restrict__ bias,
                                                   bf16* __restrict__ out, int N,
                                                   const int* __restrict__ cnt) {
    __shared__ bf16x8 wlds[8 * KCH * 64];
    int isbf = (*cnt == 0);
    int tid = threadIdx.x;
    stage_W<KCH>(W, wlds, tid, isbf);
    int wave = tid >> 6, lane = tid & 63;
    int quad = lane >> 4, l16 = lane & 15;
    float bb[8][4];
    load_bias(bias, quad, isbf, bb);
    __syncthreads();

    int a0bf = A0RT ? isbf : 0;
    const int na = (KCH == 8) ? 4 : KCH;
    int ntiles = N >> 4;
    int wstep = gridDim.x * 8;
    for (int tile = blockIdx.x * 8 + wave; tile < ntiles; tile += wstep) {
        int mrow = min(tile * 16 + l16, N - 1);
        bf16x8 af[KCH];
        if (KCH == 8) {
            #pragma unroll
            for (int c = 4; c < KCH; ++c)
                af[c] = *reinterpret_cast<const bf16x8*>(
                    A1 + (size_t)mrow * D128 + (c - 4) * 32 + quad * 8);
        }
        if (a0bf) {
            #pragma unroll
            for (int c = 0; c < na; ++c)
                af[c] = *reinterpret_cast<const bf16x8*>(
                    (const bf16*)A0 + (size_t)mrow * D128 + c * 32 + quad * 8);
        } else {
            #pragma unroll
            for (int c = 0; c < na; ++c) {
                const f32x4* f = reinterpret_cast<const f32x4*>(
                    (const float*)A0 + (size_t)mrow * D128 + c * 32 + quad * 8);
                f32x4 a = f[0], b = f[1];
                #pragma unroll
                for (int j = 0; j < 4; ++j) {
                    af[c][j] = bf2s(__float2bfloat16(a[j]));
                    af[c][4 + j] = bf2s(__float2bfloat16(b[j]));
                }
            }
        }

        f32x4 acc[8] = {};
        #pragma unroll
        for (int t = 0; t < 8; ++t)
            #pragma unroll
            for (int c = 0; c < KCH; ++c)
                acc[t] = __builtin_amdgcn_mfma_f32_16x16x32_bf16(
                    wlds[(t * KCH + c) * 64 + lane], af[c], acc[t], 0, 0, 0);

        #pragma unroll
        for (int t = 0; t < 8; ++t) {
            short4v pk;
            #pragma unroll
            for (int i = 0; i < 4; ++i) {
                float v = acc[t][i] + bb[t][i];
                if (ACT == 1) v = sigf(v);
                else if (ACT == 2) v = sigf(fmaxf(v, 0.0f));
                pk[i] = bf2s(__float2bfloat16(v));
            }
            *reinterpret_cast<short4v*>(out + (size_t)mrow * D128 + t * 16 + quad * 4) = pk;
        }
    }
}

// ---------------------------------------------------------------------------
// COO spmm: acc[row] += val * X[col]; rows sorted. One WAVE per EPW-edge
// segment; two-phase batched inner loop (U=8) for MLP; run-length accumulate,
// atomicAdd flush on row change.
// ---------------------------------------------------------------------------
#define SPMM_U 8
#define EPW 64
__global__ __launch_bounds__(256) void spmm_kernel(const int* __restrict__ rows,
                                                   const int* __restrict__ cols,
                                                   const void* __restrict__ vals,
                                                   const bf16* __restrict__ X,
                                                   float* __restrict__ acc, int E,
                                                   const int* __restrict__ cnt) {
    int isbf = (*cnt == 0);
    int wave = threadIdx.x >> 6, lane = threadIdx.x & 63;
    int e0 = (blockIdx.x * 4 + wave) * EPW;
    if (e0 >= E) return;
    int e1 = min(e0 + EPW, E);
    int prev = rows[e0];
    float a0 = 0.f, a1 = 0.f;
    for (int base = e0; base < e1; base += SPMM_U) {
        int nb = e1 - base;  // >= 1
        int rr[SPMM_U];
        float vv[SPMM_U];
        float x0[SPMM_U], x1[SPMM_U];
        #pragma unroll
        for (int u = 0; u < SPMM_U; ++u) {
            int e = base + (u < nb ? u : nb - 1);
            int c = cols[e];
            rr[u] = rows[e];
            float v = loadf(vals, e, isbf);
            vv[u] = (u < nb) ? v : 0.f;
            __hip_bfloat162 x2 = ((const __hip_bfloat162*)(X + (size_t)c * D128))[lane];
            x0[u] = __bfloat162float(x2.x);
            x1[u] = __bfloat162float(x2.y);
        }
        #pragma unroll
        for (int u = 0; u < SPMM_U; ++u) {
            if (rr[u] != prev) {
                atomicAdd(&acc[(size_t)prev * D128 + 2 * lane], a0);
                atomicAdd(&acc[(size_t)prev * D128 + 2 * lane + 1], a1);
                a0 = 0.f; a1 = 0.f;
                prev = rr[u];
            }
            a0 += vv[u] * x0[u];
            a1 += vv[u] * x1[u];
        }
    }
    atomicAdd(&acc[(size_t)prev * D128 + 2 * lane], a0);
    atomicAdd(&acc[(size_t)prev * D128 + 2 * lane + 1], a1);
}

// final_group = sig((sig(agg_gi) + first + second) * 0.5)
__global__ __launch_bounds__(256) void fgroup_kernel(const float* __restrict__ agg,
                                                     const bf16* __restrict__ f1,
                                                     const bf16* __restrict__ f2,
                                                     bf16* __restrict__ out, int n) {
    int i = blockIdx.x * 256 + threadIdx.x;
    if (i < n) {
        float v = (sigf(agg[i]) + __bfloat162float(f1[i]) +
                   __bfloat162float(f2[i])) * 0.5f;
        out[i] = __float2bfloat16(sigf(v));
    }
}

// Scoring: one wave per (group,item) pair; 2 columns per lane.
__global__ __launch_bounds__(256) void score_kernel(const int* __restrict__ gids,
                                                    const int* __restrict__ iids,
                                                    const bf16* __restrict__ FG,
                                                    const bf16* __restrict__ FI,
                                                    const float* __restrict__ NB,
                                                    void* __restrict__ out, int Bn,
                                                    const int* __restrict__ cnt) {
    int isbf = (*cnt == 0);
    int w = blockIdx.x * 4 + (threadIdx.x >> 6);
    int lane = threadIdx.x & 63;
    if (w >= Bn) return;
    int g = gids[w];
    int it = iids[w];
    __hip_bfloat162 ge2 = ((const __hip_bfloat162*)(FG + (size_t)g * D128))[lane];
    __hip_bfloat162 ie2 = ((const __hip_bfloat162*)(FI + (size_t)it * D128))[lane];
    float2 ne2 = ((const float2*)(NB + (size_t)g * D128))[lane];
    float ge0 = __bfloat162float(ge2.x), ge1 = __bfloat162float(ge2.y);
    float ie0 = __bfloat162float(ie2.x), ie1 = __bfloat162float(ie2.y);
    float gi = ge0 * ie0 + ge1 * ie1;
    float ng = ne2.x * ge0 + ne2.y * ge1;
    float ni = ne2.x * ie0 + ne2.y * ie1;
    #pragma unroll
    for (int o = 32; o >= 1; o >>= 1) {
        gi += __shfl_xor(gi, o);
        ng += __shfl_xor(ng, o);
        ni += __shfl_xor(ni, o);
    }
    if (lane == 0) {
        if (isbf) {
            ((bf16*)out)[w] = __float2bfloat16(gi);
            ((bf16*)out)[Bn + w] = __float2bfloat16(ng + ni);
        } else {
            ((float*)out)[w] = gi;
            ((float*)out)[Bn + w] = ng + ni;
        }
    }
}

// ---------------------------------------------------------------------------
extern "C" void kernel_launch(void* const* d_in, const int* in_sizes, int n_in,
                              void* d_out, int out_size, void* d_ws, size_t ws_size,
                              hipStream_t stream) {
    const int* group_ids = (const int*)d_in[0];
    const int* item_ids  = (const int*)d_in[1];
    const int* gi_rows   = (const int*)d_in[2];
    const int* gi_cols   = (const int*)d_in[3];
    const void* gi_vals  = d_in[4];
    const int* gg_rows   = (const int*)d_in[5];
    const int* gg_cols   = (const int*)d_in[6];
    const void* gg_vals  = d_in[7];
    const void* g_feat   = d_in[8];
    const void* i_feat   = d_in[9];
    const void* emb_group = d_in[10];
    const void* emb_item  = d_in[11];
    const void* W_w       = d_in[12];
    const void* W_b       = d_in[13];
    const void* red_w     = d_in[14];
    const void* red_b     = d_in[15];
    const void* item_fus_w = d_in[16];
    const void* item_fus_b = d_in[17];
    const void* group_fus_w = d_in[18];
    const void* group_fus_b = d_in[19];

    const int Bn = in_sizes[0];
    const int E  = in_sizes[2];
    const int NG = in_sizes[8] / D128;
    const int NI = in_sizes[9] / D128;

    // ---- workspace layout (89.6 MB + 4 B) ----
    const size_t NGD2 = (size_t)NG * D128 * 2;  // bf16 group block
    const size_t NID2 = (size_t)NI * D128 * 2;  // bf16 item block
    const size_t NGD4 = (size_t)NG * D128 * 4;  // f32 group block
    char* ws = (char*)d_ws;
    float* agg   = (float*)(ws);                          // f32 spmm accumulator
    bf16* itemB  = (bf16*)(ws + NGD4);                    // i2 -> finalItem (in-place)
    bf16* gB     = (bf16*)(ws + NGD4 + NID2);             // g2 -> fusG -> finalG
    bf16* firstB = (bf16*)(ws + NGD4 + NID2 + NGD2);      // first
    bf16* secondB= (bf16*)(ws + NGD4 + NID2 + 2 * NGD2);  // second
    int*  cnt    = (int*)(ws + NGD4 + NID2 + 3 * NGD2);   // dtype sniff result

    const int ngd = NG * D128;
    const int tilesG = NG >> 4, tilesI = NI >> 4;
    const int gridG = min((tilesG + 7) / 8, 512);
    const int gridI = min((tilesI + 7) / 8, 512);
    const int ewG = (ngd + 255) / 256;
    const int spmmB = (E + EPW * 4 - 1) / (EPW * 4);

    // 0: dtype sniff
    sniff_kernel<<<1, 256, 0, stream>>>((const unsigned short*)g_feat, cnt);
    // 1-2: g2 = inorm(inorm(g_feat)@red_w^T+red_b); i2 likewise
    ngn_kernel<<<gridG, 512, 0, stream>>>(g_feat, red_w, red_b, gB, NG, cnt);
    ngn_kernel<<<gridI, 512, 0, stream>>>(i_feat, red_w, red_b, itemB, NI, cnt);
    // 3: finalItem = sig([emb_item | i2] @ item_fus_w^T + b)   (in-place over i2)
    gemm_kernel<8, 1, true><<<gridI, 512, 0, stream>>>(emb_item, itemB, item_fus_w,
                                                       item_fus_b, itemB, NI, cnt);
    // 4: fusG = sig([emb_group | g2] @ group_fus_w^T + b)      (in-place over g2)
    gemm_kernel<8, 1, true><<<gridG, 512, 0, stream>>>(emb_group, gB, group_fus_w,
                                                       group_fus_b, gB, NG, cnt);
    // 5-7: first = sig(relu(spmm(gg, fusG) @ W_w^T + W_b))
    hipMemsetAsync(agg, 0, NGD4, stream);
    spmm_kernel<<<spmmB, 256, 0, stream>>>(gg_rows, gg_cols, gg_vals, gB, agg, E, cnt);
    gemm_kernel<4, 2, false><<<gridG, 512, 0, stream>>>(agg, nullptr, W_w, W_b,
                                                        firstB, NG, cnt);
    // 8-10: second = sig(relu(spmm(gg, first) @ W_w^T + W_b))
    hipMemsetAsync(agg, 0, NGD4, stream);
    spmm_kernel<<<spmmB, 256, 0, stream>>>(gg_rows, gg_cols, gg_vals, firstB, agg, E, cnt);
    gemm_kernel<4, 2, false><<<gridG, 512, 0, stream>>>(agg, nullptr, W_w, W_b,
                                                        secondB, NG, cnt);
    // 11-12: agg = spmm(gi, finalItem)
    hipMemsetAsync(agg, 0, NGD4, stream);
    spmm_kernel<<<spmmB, 256, 0, stream>>>(gi_rows, gi_cols, gi_vals, itemB, agg, E, cnt);
    // 13: finalG = sig((sig(agg) + first + second)/2)          (over fusG slot)
    fgroup_kernel<<<ewG, 256, 0, stream>>>(agg, firstB, secondB, gB, ngd);
    // 14-15: agg = spmm(gg, finalG)
    hipMemsetAsync(agg, 0, NGD4, stream);
    spmm_kernel<<<spmmB, 256, 0, stream>>>(gg_rows, gg_cols, gg_vals, gB, agg, E, cnt);
    // 16: scoring
    score_kernel<<<(Bn + 3) / 4, 256, 0, stream>>>(group_ids, item_ids, gB, itemB,
                                                   agg, d_out, Bn, cnt);
}

// Round 6
// 670.004 us; speedup vs baseline: 1.1231x; 1.1231x over previous
//
#include <hip/hip_runtime.h>
#include <hip/hip_bf16.h>

typedef __hip_bfloat16 bf16;
typedef __attribute__((ext_vector_type(8))) short bf16x8;
typedef __attribute__((ext_vector_type(4))) float f32x4;

#define D128 128

// fast sigmoid: rcp(1+exp2(-x*log2e)) — error far below bf16 ulp (R5-validated)
__device__ __forceinline__ float sigf(float x) {
    float e = __builtin_amdgcn_exp2f(-1.44269504f * x);
    return __builtin_amdgcn_rcpf(1.0f + e);
}

__device__ __forceinline__ short bf2s(bf16 h) { union { bf16 h; short s; } u; u.h = h; return u.s; }
__device__ __forceinline__ float s2f(short s) { union { short s; bf16 h; } u; u.s = s; return __bfloat162float(u.h); }

__device__ __forceinline__ float loadf(const void* p, size_t off, int isbf) {
    return isbf ? __bfloat162float(((const bf16*)p)[off]) : ((const float*)p)[off];
}

// ---------------------------------------------------------------------------
// Dtype sniffer: count bf16 exponent-all-ones patterns in first 16384 ushorts
// of g_feat. bf16 N(0,1) -> 0; f32-as-ushorts -> ~32. (*cnt==0) == "bf16".
// ---------------------------------------------------------------------------
__global__ __launch_bounds__(256) void sniff_kernel(const unsigned short* __restrict__ g,
                                                    int* __restrict__ cnt) {
    int t = threadIdx.x;
    int c = 0;
    for (int i = t; i < 16384; i += 256) {
        unsigned short u = g[i];
        if ((u & 0x7F80u) == 0x7F80u) c++;
    }
    #pragma unroll
    for (int o = 32; o >= 1; o >>= 1) c += __shfl_xor(c, o);
    __shared__ int sh[4];
    if ((t & 63) == 0) sh[t >> 6] = c;
    __syncthreads();
    if (t == 0) *cnt = sh[0] + sh[1] + sh[2] + sh[3];
}

// ---------------------------------------------------------------------------
// One-time weight prep: W (128 x K raw) -> bf16 B-operand fragments in ws:
// wf[(t*KCH+c)*64 + l] = W[t*16+(l&15)][c*32+(l>>4)*8 .. +8]  (16 B each,
// lane-contiguous 1 KB per (t,c) -> coalesced wave loads in the GEMMs).
// Also bias (128 raw) -> f32. Launch with >= 8*KCH*64 threads.
// ---------------------------------------------------------------------------
template <int KCH>
__global__ __launch_bounds__(256) void prep_w(const void* __restrict__ W,
                                              bf16x8* __restrict__ wf,
                                              const void* __restrict__ bias,
                                              float* __restrict__ bias_f,
                                              const int* __restrict__ cnt) {
    int isbf = (*cnt == 0);
    const int K = KCH * 32;
    int idx = blockIdx.x * 256 + threadIdx.x;
    const int total = 8 * KCH * 64;
    if (idx < total) {
        int t = idx / (KCH * 64);
        int c = (idx / 64) % KCH;
        int l = idx & 63;
        int row = t * 16 + (l & 15);
        int off = c * 32 + (l >> 4) * 8;
        bf16x8 r;
        if (isbf) {
            r = *reinterpret_cast<const bf16x8*>((const bf16*)W + (size_t)row * K + off);
        } else {
            const f32x4* f = reinterpret_cast<const f32x4*>((const float*)W + (size_t)row * K + off);
            f32x4 a = f[0], b = f[1];
            #pragma unroll
            for (int j = 0; j < 4; ++j) {
                r[j] = bf2s(__float2bfloat16(a[j]));
                r[4 + j] = bf2s(__float2bfloat16(b[j]));
            }
        }
        wf[idx] = r;
    }
    if (idx < D128) bias_f[idx] = loadf(bias, idx, isbf);
}

// ---------------------------------------------------------------------------
// Fused: out = inorm(inorm(X) @ W^T + b). No LDS, no barriers: W read as
// pre-converted fragments from global (L2-resident). One wave = one 16-row
// tile. A-operand = X rows (row=l16, k=quad*8+j); C/D: row=quad*4+i, col=
// t*16+l16 -> stores have lanes contiguous in columns (R4-proven clean).
// ---------------------------------------------------------------------------
__global__ __launch_bounds__(256) void ngn_kernel(const void* __restrict__ X,
                                                  const bf16x8* __restrict__ wf,
                                                  const float* __restrict__ bias_f,
                                                  bf16* __restrict__ out, int N,
                                                  const int* __restrict__ cnt) {
    int isbf = (*cnt == 0);
    int tid = threadIdx.x;
    int wave = tid >> 6, lane = tid & 63;
    int quad = lane >> 4, l16 = lane & 15;
    int tile = blockIdx.x * 4 + wave;
    if (tile * 16 >= N) return;
    int mrow = tile * 16 + l16;

    // load input row, first inorm (row spread across quads, same l16)
    float x[4][8];
    if (isbf) {
        #pragma unroll
        for (int c = 0; c < 4; ++c) {
            bf16x8 v = *reinterpret_cast<const bf16x8*>(
                (const bf16*)X + (size_t)mrow * D128 + c * 32 + quad * 8);
            #pragma unroll
            for (int j = 0; j < 8; ++j) x[c][j] = s2f(v[j]);
        }
    } else {
        #pragma unroll
        for (int c = 0; c < 4; ++c) {
            const f32x4* f = reinterpret_cast<const f32x4*>(
                (const float*)X + (size_t)mrow * D128 + c * 32 + quad * 8);
            f32x4 a = f[0], b = f[1];
            #pragma unroll
            for (int j = 0; j < 4; ++j) { x[c][j] = a[j]; x[c][4 + j] = b[j]; }
        }
    }
    float s = 0.f, ss = 0.f;
    #pragma unroll
    for (int c = 0; c < 4; ++c)
        #pragma unroll
        for (int j = 0; j < 8; ++j) { s += x[c][j]; ss += x[c][j] * x[c][j]; }
    s += __shfl_xor(s, 16); ss += __shfl_xor(ss, 16);
    s += __shfl_xor(s, 32); ss += __shfl_xor(ss, 32);
    float mean = s * (1.0f / 128.0f);
    float var = ss * (1.0f / 128.0f) - mean * mean;
    float rinv = rsqrtf(fmaxf(var, 0.f) + 1e-5f);

    bf16x8 af[4];
    #pragma unroll
    for (int c = 0; c < 4; ++c)
        #pragma unroll
        for (int j = 0; j < 8; ++j)
            af[c][j] = bf2s(__float2bfloat16((x[c][j] - mean) * rinv));

    f32x4 acc[8] = {};
    #pragma unroll
    for (int t = 0; t < 8; ++t)
        #pragma unroll
        for (int c = 0; c < 4; ++c)
            acc[t] = __builtin_amdgcn_mfma_f32_16x16x32_bf16(
                af[c], wf[(t * 4 + c) * 64 + lane], acc[t], 0, 0, 0);

    // + bias, second inorm over output rows (row=quad*4+i, 128 vals across
    // t x l16 within the quad) -> xor 1..8 reduction
    float vals[8][4];
    float ps[4] = {0, 0, 0, 0}, pss[4] = {0, 0, 0, 0};
    #pragma unroll
    for (int t = 0; t < 8; ++t) {
        float b = bias_f[t * 16 + l16];
        #pragma unroll
        for (int i = 0; i < 4; ++i) {
            float v = acc[t][i] + b;
            vals[t][i] = v;
            ps[i] += v; pss[i] += v * v;
        }
    }
    #pragma unroll
    for (int i = 0; i < 4; ++i) {
        #pragma unroll
        for (int o = 1; o < 16; o <<= 1) {
            ps[i] += __shfl_xor(ps[i], o);
            pss[i] += __shfl_xor(pss[i], o);
        }
    }
    #pragma unroll
    for (int i = 0; i < 4; ++i) {
        int row = tile * 16 + quad * 4 + i;
        float m2 = ps[i] * (1.0f / 128.0f);
        float v2 = pss[i] * (1.0f / 128.0f) - m2 * m2;
        float r2 = rsqrtf(fmaxf(v2, 0.f) + 1e-5f);
        #pragma unroll
        for (int t = 0; t < 8; ++t)
            out[(size_t)row * D128 + t * 16 + l16] =
                __float2bfloat16((vals[t][i] - m2) * r2);
    }
}

// ---------------------------------------------------------------------------
// GEMM: out = act(X @ W^T + b). Same no-LDS structure. A0 raw input
// (flag-typed if A0RT, else f32); A1 bf16 ws buffer (concat second half when
// KCH==8). ACT: 1 sigmoid, 2 sig(relu). In-place out==A1 safe (wave reads
// only its tile's rows; loads precede stores; N%16==0 holds).
// ---------------------------------------------------------------------------
template <int KCH, int ACT, bool A0RT>
__global__ __launch_bounds__(256) void gemm_kernel(const void* __restrict__ A0,
                                                   const bf16* __restrict__ A1,
                                                   const bf16x8* __restrict__ wf,
                                                   const float* __restrict__ bias_f,
                                                   bf16* __restrict__ out, int N,
                                                   const int* __restrict__ cnt) {
    int isbf = (*cnt == 0);
    int tid = threadIdx.x;
    int wave = tid >> 6, lane = tid & 63;
    int quad = lane >> 4, l16 = lane & 15;
    int tile = blockIdx.x * 4 + wave;
    if (tile * 16 >= N) return;
    int mrow = tile * 16 + l16;

    int a0bf = A0RT ? isbf : 0;
    const int na = (KCH == 8) ? 4 : KCH;
    bf16x8 af[KCH];
    if (KCH == 8) {
        #pragma unroll
        for (int c = 4; c < KCH; ++c)
            af[c] = *reinterpret_cast<const bf16x8*>(
                A1 + (size_t)mrow * D128 + (c - 4) * 32 + quad * 8);
    }
    if (a0bf) {
        #pragma unroll
        for (int c = 0; c < na; ++c)
            af[c] = *reinterpret_cast<const bf16x8*>(
                (const bf16*)A0 + (size_t)mrow * D128 + c * 32 + quad * 8);
    } else {
        #pragma unroll
        for (int c = 0; c < na; ++c) {
            const f32x4* f = reinterpret_cast<const f32x4*>(
                (const float*)A0 + (size_t)mrow * D128 + c * 32 + quad * 8);
            f32x4 a = f[0], b = f[1];
            #pragma unroll
            for (int j = 0; j < 4; ++j) {
                af[c][j] = bf2s(__float2bfloat16(a[j]));
                af[c][4 + j] = bf2s(__float2bfloat16(b[j]));
            }
        }
    }

    f32x4 acc[8] = {};
    #pragma unroll
    for (int t = 0; t < 8; ++t)
        #pragma unroll
        for (int c = 0; c < KCH; ++c)
            acc[t] = __builtin_amdgcn_mfma_f32_16x16x32_bf16(
                af[c], wf[(t * KCH + c) * 64 + lane], acc[t], 0, 0, 0);

    #pragma unroll
    for (int t = 0; t < 8; ++t) {
        float b = bias_f[t * 16 + l16];
        #pragma unroll
        for (int i = 0; i < 4; ++i) {
            int row = tile * 16 + quad * 4 + i;
            float v = acc[t][i] + b;
            if (ACT == 1) v = sigf(v);
            else if (ACT == 2) v = sigf(fmaxf(v, 0.0f));
            out[(size_t)row * D128 + t * 16 + l16] = __float2bfloat16(v);
        }
    }
}

// ---------------------------------------------------------------------------
// COO spmm: acc[row] += val * X[col]; rows sorted. One WAVE per EPW-edge
// segment; two-phase batched inner loop (U=8) for MLP; run-length accumulate,
// atomicAdd flush on row change.
// ---------------------------------------------------------------------------
#define SPMM_U 8
#define EPW 64
__global__ __launch_bounds__(256) void spmm_kernel(const int* __restrict__ rows,
                                                   const int* __restrict__ cols,
                                                   const void* __restrict__ vals,
                                                   const bf16* __restrict__ X,
                                                   float* __restrict__ acc, int E,
                                                   const int* __restrict__ cnt) {
    int isbf = (*cnt == 0);
    int wave = threadIdx.x >> 6, lane = threadIdx.x & 63;
    int e0 = (blockIdx.x * 4 + wave) * EPW;
    if (e0 >= E) return;
    int e1 = min(e0 + EPW, E);
    int prev = rows[e0];
    float a0 = 0.f, a1 = 0.f;
    for (int base = e0; base < e1; base += SPMM_U) {
        int nb = e1 - base;  // >= 1
        int rr[SPMM_U];
        float vv[SPMM_U];
        float x0[SPMM_U], x1[SPMM_U];
        #pragma unroll
        for (int u = 0; u < SPMM_U; ++u) {
            int e = base + (u < nb ? u : nb - 1);
            int c = cols[e];
            rr[u] = rows[e];
            float v = loadf(vals, e, isbf);
            vv[u] = (u < nb) ? v : 0.f;
            __hip_bfloat162 x2 = ((const __hip_bfloat162*)(X + (size_t)c * D128))[lane];
            x0[u] = __bfloat162float(x2.x);
            x1[u] = __bfloat162float(x2.y);
        }
        #pragma unroll
        for (int u = 0; u < SPMM_U; ++u) {
            if (rr[u] != prev) {
                atomicAdd(&acc[(size_t)prev * D128 + 2 * lane], a0);
                atomicAdd(&acc[(size_t)prev * D128 + 2 * lane + 1], a1);
                a0 = 0.f; a1 = 0.f;
                prev = rr[u];
            }
            a0 += vv[u] * x0[u];
            a1 += vv[u] * x1[u];
        }
    }
    atomicAdd(&acc[(size_t)prev * D128 + 2 * lane], a0);
    atomicAdd(&acc[(size_t)prev * D128 + 2 * lane + 1], a1);
}

// final_group = sig((sig(agg_gi) + first + second) * 0.5)
__global__ __launch_bounds__(256) void fgroup_kernel(const float* __restrict__ agg,
                                                     const bf16* __restrict__ f1,
                                                     const bf16* __restrict__ f2,
                                                     bf16* __restrict__ out, int n) {
    int i = blockIdx.x * 256 + threadIdx.x;
    if (i < n) {
        float v = (sigf(agg[i]) + __bfloat162float(f1[i]) +
                   __bfloat162float(f2[i])) * 0.5f;
        out[i] = __float2bfloat16(sigf(v));
    }
}

// Scoring: one wave per (group,item) pair; 2 columns per lane.
__global__ __launch_bounds__(256) void score_kernel(const int* __restrict__ gids,
                                                    const int* __restrict__ iids,
                                                    const bf16* __restrict__ FG,
                                                    const bf16* __restrict__ FI,
                                                    const float* __restrict__ NB,
                                                    void* __restrict__ out, int Bn,
                                                    const int* __restrict__ cnt) {
    int isbf = (*cnt == 0);
    int w = blockIdx.x * 4 + (threadIdx.x >> 6);
    int lane = threadIdx.x & 63;
    if (w >= Bn) return;
    int g = gids[w];
    int it = iids[w];
    __hip_bfloat162 ge2 = ((const __hip_bfloat162*)(FG + (size_t)g * D128))[lane];
    __hip_bfloat162 ie2 = ((const __hip_bfloat162*)(FI + (size_t)it * D128))[lane];
    float2 ne2 = ((const float2*)(NB + (size_t)g * D128))[lane];
    float ge0 = __bfloat162float(ge2.x), ge1 = __bfloat162float(ge2.y);
    float ie0 = __bfloat162float(ie2.x), ie1 = __bfloat162float(ie2.y);
    float gi = ge0 * ie0 + ge1 * ie1;
    float ng = ne2.x * ge0 + ne2.y * ge1;
    float ni = ne2.x * ie0 + ne2.y * ie1;
    #pragma unroll
    for (int o = 32; o >= 1; o >>= 1) {
        gi += __shfl_xor(gi, o);
        ng += __shfl_xor(ng, o);
        ni += __shfl_xor(ni, o);
    }
    if (lane == 0) {
        if (isbf) {
            ((bf16*)out)[w] = __float2bfloat16(gi);
            ((bf16*)out)[Bn + w] = __float2bfloat16(ng + ni);
        } else {
            ((float*)out)[w] = gi;
            ((float*)out)[Bn + w] = ng + ni;
        }
    }
}

// ---------------------------------------------------------------------------
extern "C" void kernel_launch(void* const* d_in, const int* in_sizes, int n_in,
                              void* d_out, int out_size, void* d_ws, size_t ws_size,
                              hipStream_t stream) {
    const int* group_ids = (const int*)d_in[0];
    const int* item_ids  = (const int*)d_in[1];
    const int* gi_rows   = (const int*)d_in[2];
    const int* gi_cols   = (const int*)d_in[3];
    const void* gi_vals  = d_in[4];
    const int* gg_rows   = (const int*)d_in[5];
    const int* gg_cols   = (const int*)d_in[6];
    const void* gg_vals  = d_in[7];
    const void* g_feat   = d_in[8];
    const void* i_feat   = d_in[9];
    const void* emb_group = d_in[10];
    const void* emb_item  = d_in[11];
    const void* W_w       = d_in[12];
    const void* W_b       = d_in[13];
    const void* red_w     = d_in[14];
    const void* red_b     = d_in[15];
    const void* item_fus_w = d_in[16];
    const void* item_fus_b = d_in[17];
    const void* group_fus_w = d_in[18];
    const void* group_fus_b = d_in[19];

    const int Bn = in_sizes[0];
    const int E  = in_sizes[2];
    const int NG = in_sizes[8] / D128;
    const int NI = in_sizes[9] / D128;

    // ---- workspace layout (~89.8 MB) ----
    const size_t NGD2 = (size_t)NG * D128 * 2;  // bf16 group block
    const size_t NID2 = (size_t)NI * D128 * 2;  // bf16 item block
    const size_t NGD4 = (size_t)NG * D128 * 4;  // f32 group block
    char* ws = (char*)d_ws;
    float* agg   = (float*)(ws);                          // f32 spmm accumulator
    bf16* itemB  = (bf16*)(ws + NGD4);                    // i2 -> finalItem (in-place)
    bf16* gB     = (bf16*)(ws + NGD4 + NID2);             // g2 -> fusG -> finalG
    bf16* firstB = (bf16*)(ws + NGD4 + NID2 + NGD2);      // first
    bf16* secondB= (bf16*)(ws + NGD4 + NID2 + 2 * NGD2);  // second
    char* xtra   = ws + NGD4 + NID2 + 3 * NGD2;
    bf16x8* wf_red  = (bf16x8*)(xtra);                    // 32 KB
    bf16x8* wf_W    = (bf16x8*)(xtra + 32 * 1024);        // 32 KB
    bf16x8* wf_ifus = (bf16x8*)(xtra + 64 * 1024);        // 64 KB
    bf16x8* wf_gfus = (bf16x8*)(xtra + 128 * 1024);       // 64 KB
    float* b_red  = (float*)(xtra + 192 * 1024);
    float* b_W    = (float*)(xtra + 192 * 1024 + 512);
    float* b_ifus = (float*)(xtra + 192 * 1024 + 1024);
    float* b_gfus = (float*)(xtra + 192 * 1024 + 1536);
    int*  cnt     = (int*)(xtra + 194 * 1024);

    const int ngd = NG * D128;
    const int tilesG = NG >> 4, tilesI = NI >> 4;
    const int gridG = (tilesG + 3) / 4;
    const int gridI = (tilesI + 3) / 4;
    const int ewG = (ngd + 255) / 256;
    const int spmmB = (E + EPW * 4 - 1) / (EPW * 4);

    // 0: dtype sniff + weight prep
    sniff_kernel<<<1, 256, 0, stream>>>((const unsigned short*)g_feat, cnt);
    prep_w<4><<<8, 256, 0, stream>>>(red_w, wf_red, red_b, b_red, cnt);
    prep_w<4><<<8, 256, 0, stream>>>(W_w, wf_W, W_b, b_W, cnt);
    prep_w<8><<<16, 256, 0, stream>>>(item_fus_w, wf_ifus, item_fus_b, b_ifus, cnt);
    prep_w<8><<<16, 256, 0, stream>>>(group_fus_w, wf_gfus, group_fus_b, b_gfus, cnt);
    // 1-2: g2 = inorm(inorm(g_feat)@red_w^T+red_b); i2 likewise
    ngn_kernel<<<gridG, 256, 0, stream>>>(g_feat, wf_red, b_red, gB, NG, cnt);
    ngn_kernel<<<gridI, 256, 0, stream>>>(i_feat, wf_red, b_red, itemB, NI, cnt);
    // 3: finalItem = sig([emb_item | i2] @ item_fus_w^T + b)   (in-place over i2)
    gemm_kernel<8, 1, true><<<gridI, 256, 0, stream>>>(emb_item, itemB, wf_ifus,
                                                       b_ifus, itemB, NI, cnt);
    // 4: fusG = sig([emb_group | g2] @ group_fus_w^T + b)      (in-place over g2)
    gemm_kernel<8, 1, true><<<gridG, 256, 0, stream>>>(emb_group, gB, wf_gfus,
                                                       b_gfus, gB, NG, cnt);
    // 5-7: first = sig(relu(spmm(gg, fusG) @ W_w^T + W_b))
    hipMemsetAsync(agg, 0, NGD4, stream);
    spmm_kernel<<<spmmB, 256, 0, stream>>>(gg_rows, gg_cols, gg_vals, gB, agg, E, cnt);
    gemm_kernel<4, 2, false><<<gridG, 256, 0, stream>>>(agg, nullptr, wf_W, b_W,
                                                        firstB, NG, cnt);
    // 8-10: second = sig(relu(spmm(gg, first) @ W_w^T + W_b))
    hipMemsetAsync(agg, 0, NGD4, stream);
    spmm_kernel<<<spmmB, 256, 0, stream>>>(gg_rows, gg_cols, gg_vals, firstB, agg, E, cnt);
    gemm_kernel<4, 2, false><<<gridG, 256, 0, stream>>>(agg, nullptr, wf_W, b_W,
                                                        secondB, NG, cnt);
    // 11-12: agg = spmm(gi, finalItem)
    hipMemsetAsync(agg, 0, NGD4, stream);
    spmm_kernel<<<spmmB, 256, 0, stream>>>(gi_rows, gi_cols, gi_vals, itemB, agg, E, cnt);
    // 13: finalG = sig((sig(agg) + first + second)/2)          (over fusG slot)
    fgroup_kernel<<<ewG, 256, 0, stream>>>(agg, firstB, secondB, gB, ngd);
    // 14-15: agg = spmm(gg, finalG)
    hipMemsetAsync(agg, 0, NGD4, stream);
    spmm_kernel<<<spmmB, 256, 0, stream>>>(gg_rows, gg_cols, gg_vals, gB, agg, E, cnt);
    // 16: scoring
    score_kernel<<<(Bn + 3) / 4, 256, 0, stream>>>(group_ids, item_ids, gB, itemB,
                                                   agg, d_out, Bn, cnt);
}